// Round 7
// baseline (560.663 us; speedup 1.0000x reference)
//
#include <hip/hip_runtime.h>
#include <hip/hip_bf16.h>
#include <math.h>

#define K_DIM 256
using bf16 = __hip_bfloat16;

// ---- dtype helpers ------------------------------------------------------
__device__ __forceinline__ float b2f(unsigned short u) {
    return __uint_as_float(((unsigned)u) << 16);
}
__device__ __forceinline__ unsigned short f2b(float f) {   // RNE f32->bf16
    unsigned u = __float_as_uint(f);
    unsigned r = 0x7FFFu + ((u >> 16) & 1u);
    return (unsigned short)((u + r) >> 16);
}
__device__ __forceinline__ float  ld1(const float* p) { return *p; }
__device__ __forceinline__ float  ld1(const bf16*  p) { return b2f(*(const unsigned short*)p); }
__device__ __forceinline__ void   st1(float* p, float v) { *p = v; }
__device__ __forceinline__ void   st1(bf16*  p, float v) { *(unsigned short*)p = f2b(v); }
__device__ __forceinline__ float4 ld4(const float* p) { return *(const float4*)p; }
__device__ __forceinline__ float4 ld4(const bf16*  p) {
    ushort4 u = *(const ushort4*)p;
    return make_float4(b2f(u.x), b2f(u.y), b2f(u.z), b2f(u.w));
}

// ---- runtime dtype detection (insurance; evidence says f32) -------------
// For bf16-packed u32s, bits 8..14 are the low element's top-7 exponent
// bits: N(0,1) bf16 data lands in [0x3C,0x40] ~99% of the time. For f32
// data those are mantissa bits (~uniform, ~6% hit). Ballot over 64 words.
__device__ __forceinline__ bool detect_bf16(const unsigned* __restrict__ qw) {
    unsigned w = qw[threadIdx.x & 63];
    unsigned t = (w >> 8) & 0x7F;
    bool hit = (t >= 0x3Bu) && (t <= 0x42u);
    unsigned long long m = __ballot(hit);
    return __popcll(m) >= 32;
}

// ---- GEMM body ----------------------------------------------------------
// C[M,N] = (A1 (+A2))[M,256] @ W[N,256]^T + bias[N] (+ Res[M,N]); f32 math.
template<typename AT, typename IT, typename CT, bool ADD_A2, bool ADD_RES>
__device__ __forceinline__ void gemm_body(
    const AT* __restrict__ A1, const IT* __restrict__ A2,
    const IT* __restrict__ W, const IT* __restrict__ bias,
    const IT* __restrict__ Res, CT* __restrict__ C, int M, int N)
{
    __shared__ float As[16][65];
    __shared__ float Bs[16][65];
    const int tid = threadIdx.x;
    const int bm = blockIdx.y * 64;
    const int bn = blockIdx.x * 64;
    const int tx = tid & 15;
    const int ty = tid >> 4;
    const int lr = tid >> 2;
    const int lc = (tid & 3) * 4;

    float acc[4][4] = {};

    for (int k0 = 0; k0 < K_DIM; k0 += 16) {
        float4 av = ld4(A1 + (size_t)(bm + lr) * K_DIM + k0 + lc);
        if (ADD_A2) {
            float4 a2 = ld4(A2 + (size_t)(bm + lr) * K_DIM + k0 + lc);
            av.x += a2.x; av.y += a2.y; av.z += a2.z; av.w += a2.w;
        }
        As[lc + 0][lr] = av.x;
        As[lc + 1][lr] = av.y;
        As[lc + 2][lr] = av.z;
        As[lc + 3][lr] = av.w;
        float4 bv = ld4(W + (size_t)(bn + lr) * K_DIM + k0 + lc);
        Bs[lc + 0][lr] = bv.x;
        Bs[lc + 1][lr] = bv.y;
        Bs[lc + 2][lr] = bv.z;
        Bs[lc + 3][lr] = bv.w;
        __syncthreads();
        #pragma unroll
        for (int k = 0; k < 16; ++k) {
            float a[4], b[4];
            #pragma unroll
            for (int i = 0; i < 4; ++i) a[i] = As[k][ty * 4 + i];
            #pragma unroll
            for (int j = 0; j < 4; ++j) b[j] = Bs[k][tx * 4 + j];
            #pragma unroll
            for (int i = 0; i < 4; ++i)
                #pragma unroll
                for (int j = 0; j < 4; ++j)
                    acc[i][j] = fmaf(a[i], b[j], acc[i][j]);
        }
        __syncthreads();
    }

    #pragma unroll
    for (int i = 0; i < 4; ++i) {
        const int row = bm + ty * 4 + i;
        #pragma unroll
        for (int j = 0; j < 4; ++j) {
            const int col = bn + tx * 4 + j;
            float v = acc[i][j] + ld1(bias + col);
            if (ADD_RES) v += ld1(Res + (size_t)row * N + col);
            st1(C + (size_t)row * N + col, v);
        }
    }
}

// Input-typed GEMM -> bf16 workspace intermediate.
template<bool ADD_A2>
__global__ __launch_bounds__(256) void k_gemm_in(
    const unsigned* __restrict__ qd, const void* A1, const void* A2,
    const void* W, const void* bias, bf16* C, int M, int N)
{
    if (detect_bf16(qd))
        gemm_body<bf16, bf16, bf16, ADD_A2, false>((const bf16*)A1, (const bf16*)A2,
            (const bf16*)W, (const bf16*)bias, nullptr, C, M, N);
    else
        gemm_body<float, float, bf16, ADD_A2, false>((const float*)A1, (const float*)A2,
            (const float*)W, (const float*)bias, nullptr, C, M, N);
}

// Final GEMM: bf16 A (sampled), input-typed W/bias/Res, input-typed d_out.
__global__ __launch_bounds__(256) void k_gemm_final(
    const unsigned* __restrict__ qd, const bf16* A1,
    const void* W, const void* bias, const void* Res, void* C, int M, int N)
{
    if (detect_bf16(qd))
        gemm_body<bf16, bf16, bf16, false, true>(A1, nullptr,
            (const bf16*)W, (const bf16*)bias, (const bf16*)Res, (bf16*)C, M, N);
    else
        gemm_body<bf16, float, float, false, true>(A1, nullptr,
            (const float*)W, (const float*)bias, (const float*)Res, (float*)C, M, N);
}

// ---- sampling -----------------------------------------------------------
__device__ __forceinline__ float msda_accumulate(
    const bf16* __restrict__ vproj, const float* soff, const float* sw,
    const float* sref, int h, int ch)
{
    const int Hs[4]     = {128, 64, 32, 16};
    const int starts[4] = {0, 16384, 20480, 21504};
    float acc = 0.f;
    #pragma unroll
    for (int l = 0; l < 4; ++l) {
        const int HH = Hs[l];
        const int WW = Hs[l];
        const int st = starts[l];
        const float rx = sref[l * 2 + 0];
        const float ry = sref[l * 2 + 1];
        #pragma unroll
        for (int p = 0; p < 4; ++p) {
            const float ox = soff[h * 32 + l * 8 + p * 2 + 0];
            const float oy = soff[h * 32 + l * 8 + p * 2 + 1];
            const float gx = rx * (float)WW + ox - 0.5f;
            const float gy = ry * (float)HH + oy - 0.5f;
            const float x0f = floorf(gx);
            const float y0f = floorf(gy);
            const float wx = gx - x0f;
            const float wy = gy - y0f;
            const int x0 = (int)x0f;
            const int y0 = (int)y0f;
            const float aw = sw[h * 16 + l * 4 + p];
            const float w00 = (1.f - wx) * (1.f - wy) * aw;
            const float w10 = wx * (1.f - wy) * aw;
            const float w01 = (1.f - wx) * wy * aw;
            const float w11 = wx * wy * aw;
            const bool vx0 = (x0 >= 0) & (x0 < WW);
            const bool vx1 = (x0 + 1 >= 0) & (x0 + 1 < WW);
            if (y0 >= 0 && y0 < HH) {
                const size_t rowb = (size_t)(st + y0 * WW) * 256 + ch;
                if (vx0) acc += w00 * ld1(vproj + rowb + (size_t)x0 * 256);
                if (vx1) acc += w10 * ld1(vproj + rowb + (size_t)(x0 + 1) * 256);
            }
            if (y0 + 1 >= 0 && y0 + 1 < HH) {
                const size_t rowb = (size_t)(st + (y0 + 1) * WW) * 256 + ch;
                if (vx0) acc += w01 * ld1(vproj + rowb + (size_t)x0 * 256);
                if (vx1) acc += w11 * ld1(vproj + rowb + (size_t)(x0 + 1) * 256);
            }
        }
    }
    return acc;
}

__device__ __forceinline__ void softmax16(const float* in, float* out, int t)
{
    if (t < 8) {
        float m = -1e30f;
        #pragma unroll
        for (int i = 0; i < 16; ++i) m = fmaxf(m, in[t * 16 + i]);
        float e[16];
        float s = 0.f;
        #pragma unroll
        for (int i = 0; i < 16; ++i) { e[i] = __expf(in[t * 16 + i] - m); s += e[i]; }
        const float inv = 1.f / s;
        #pragma unroll
        for (int i = 0; i < 16; ++i) out[t * 16 + i] = e[i] * inv;
    }
}

// One block per query. osb holds offsets on entry, sampled on exit
// (in-place safe: each block stages only its own row in LDS first).
template<typename IT, bool HAS_LOGITS>
__device__ __forceinline__ void sample_body(
    const bf16* __restrict__ vproj, bf16* __restrict__ osb,
    const bf16* __restrict__ logits,
    const IT* __restrict__ query, const IT* __restrict__ query_pos,
    const IT* __restrict__ W_attn, const IT* __restrict__ b_attn,
    const IT* __restrict__ refp)
{
    const int q = blockIdx.x;
    const int t = threadIdx.x;
    const int h = t >> 5;
    const int d = t & 31;

    __shared__ float soff[256];
    __shared__ float slog[128];
    __shared__ float sw[128];
    __shared__ float sref[8];
    __shared__ float sq[256];

    soff[t] = ld1(osb + (size_t)q * 256 + t);
    if (t < 8) sref[t] = ld1(refp + (size_t)q * 8 + t);

    if (HAS_LOGITS) {
        if (t < 128) slog[t] = ld1(logits + (size_t)q * 128 + t);
        __syncthreads();
    } else {
        sq[t] = ld1(query + (size_t)q * 256 + t) + ld1(query_pos + (size_t)q * 256 + t);
        __syncthreads();
        const int lane = t & 31;
        const int sub = t >> 5;
        for (int pass = 0; pass < 16; ++pass) {
            const int c = pass * 8 + sub;
            float a = 0.f;
            #pragma unroll
            for (int j = 0; j < 8; ++j) {
                const int k = lane + 32 * j;
                a = fmaf(sq[k], ld1(W_attn + (size_t)c * 256 + k), a);
            }
            #pragma unroll
            for (int m = 16; m >= 1; m >>= 1) a += __shfl_xor(a, m, 64);
            if (lane == 0) slog[c] = a + ld1(b_attn + c);
        }
        __syncthreads();
    }

    softmax16(slog, sw, t);
    __syncthreads();

    const float acc = msda_accumulate(vproj, soff, sw, sref, h, h * 32 + d);
    st1(osb + (size_t)q * 256 + t, acc);
}

template<bool HAS_LOGITS>
__global__ __launch_bounds__(256) void k_sample(
    const unsigned* __restrict__ qd, const bf16* vproj, bf16* osb,
    const bf16* logits, const void* query, const void* query_pos,
    const void* W_attn, const void* b_attn, const void* refp)
{
    if (detect_bf16(qd))
        sample_body<bf16, HAS_LOGITS>(vproj, osb, logits,
            (const bf16*)query, (const bf16*)query_pos, (const bf16*)W_attn,
            (const bf16*)b_attn, (const bf16*)refp);
    else
        sample_body<float, HAS_LOGITS>(vproj, osb, logits,
            (const float*)query, (const float*)query_pos, (const float*)W_attn,
            (const float*)b_attn, (const float*)refp);
}

extern "C" void kernel_launch(void* const* d_in, const int* in_sizes, int n_in,
                              void* d_out, int out_size, void* d_ws, size_t ws_size,
                              hipStream_t stream) {
    const void* query     = d_in[0];
    const void* query_pos = d_in[1];
    const void* value     = d_in[2];
    const void* refp      = d_in[3];
    // d_in[4] spatial_shapes (int32): compile-time constants {128,64,32,16}^2
    const void* W_value = d_in[5];
    const void* b_value = d_in[6];
    const void* W_off   = d_in[7];
    const void* b_off   = d_in[8];
    const void* W_attn  = d_in[9];
    const void* b_attn  = d_in[10];
    const void* W_out   = d_in[11];
    const void* b_out   = d_in[12];
    const unsigned* qd = (const unsigned*)d_in[0];  // dtype-detect words

    const int M = in_sizes[0] / 256;   // 21760 = 64 * 340
    char* wsb = (char*)d_ws;

    // Unified bf16-intermediate layout, valid for BOTH input dtypes:
    //   [0,          M*512)  : vproj   (M x 256 bf16)
    //   [M*512,      M*1024) : osb     (offsets -> sampled in-place, bf16)
    //   [M*1024,     M*1280) : logits  (M x 128 bf16, only if ws allows)
    bf16* vproj = (bf16*)wsb;
    bf16* osb   = (bf16*)(wsb + (size_t)M * 512);
    bf16* logit = (bf16*)(wsb + (size_t)M * 1024);
    const bool sep_attn = ws_size >= (size_t)M * 1280;

    dim3 blk(256, 1, 1);
    dim3 gv(4, M / 64, 1);
    dim3 ga(2, M / 64, 1);
    dim3 gs((unsigned)M, 1, 1);

    // v = value @ W_value^T + b_value            -> vproj (bf16)
    k_gemm_in<false><<<gv, blk, 0, stream>>>(qd, value, nullptr, W_value, b_value, vproj, M, 256);
    // offsets = (q+qp) @ W_off^T + b_off         -> osb (bf16)
    k_gemm_in<true><<<gv, blk, 0, stream>>>(qd, query, query_pos, W_off, b_off, osb, M, 256);
    if (sep_attn) {
        // logits = (q+qp) @ W_attn^T + b_attn    -> logit (bf16)
        k_gemm_in<true><<<ga, blk, 0, stream>>>(qd, query, query_pos, W_attn, b_attn, logit, M, 128);
        k_sample<true><<<gs, blk, 0, stream>>>(qd, vproj, osb, logit, query, query_pos, W_attn, b_attn, refp);
    } else {
        k_sample<false><<<gs, blk, 0, stream>>>(qd, vproj, osb, nullptr, query, query_pos, W_attn, b_attn, refp);
    }
    // out = sampled @ W_out^T + b_out + query    -> d_out (input dtype)
    k_gemm_final<<<gv, blk, 0, stream>>>(qd, osb, W_out, b_out, query, d_out, M, 256);
}

// Round 8
// 297.202 us; speedup vs baseline: 1.8865x; 1.8865x over previous
//
#include <hip/hip_runtime.h>
#include <hip/hip_bf16.h>
#include <math.h>

#define K_DIM 256
using bf16 = __hip_bfloat16;

typedef __attribute__((ext_vector_type(8))) short s8v;   // 8 bf16 (4 VGPRs)
typedef __attribute__((ext_vector_type(4))) float f4v;   // 4 f32 acc

// ---- dtype helpers ------------------------------------------------------
__device__ __forceinline__ float b2f(unsigned short u) {
    return __uint_as_float(((unsigned)u) << 16);
}
__device__ __forceinline__ unsigned short f2b(float f) {   // RNE f32->bf16
    unsigned u = __float_as_uint(f);
    unsigned r = 0x7FFFu + ((u >> 16) & 1u);
    return (unsigned short)((u + r) >> 16);
}
__device__ __forceinline__ float  ld1(const float* p) { return *p; }
__device__ __forceinline__ float  ld1(const bf16*  p) { return b2f(*(const unsigned short*)p); }
__device__ __forceinline__ void   st1(float* p, float v) { *p = v; }
__device__ __forceinline__ void   st1(bf16*  p, float v) { *(unsigned short*)p = f2b(v); }
__device__ __forceinline__ float4 ld4(const float* p) { return *(const float4*)p; }
__device__ __forceinline__ float4 ld4(const bf16*  p) {
    ushort4 u = *(const ushort4*)p;
    return make_float4(b2f(u.x), b2f(u.y), b2f(u.z), b2f(u.w));
}
// 8 contiguous elements -> bf16 fragment
__device__ __forceinline__ s8v ldw8(const bf16* p) { return *(const s8v*)p; }
__device__ __forceinline__ s8v ldw8(const float* p) {
    float4 a = *(const float4*)p;
    float4 b = *(const float4*)(p + 4);
    s8v r;
    r[0] = (short)f2b(a.x); r[1] = (short)f2b(a.y); r[2] = (short)f2b(a.z); r[3] = (short)f2b(a.w);
    r[4] = (short)f2b(b.x); r[5] = (short)f2b(b.y); r[6] = (short)f2b(b.z); r[7] = (short)f2b(b.w);
    return r;
}

// ---- runtime dtype detection (insurance) --------------------------------
__device__ __forceinline__ bool detect_bf16(const unsigned* __restrict__ qw) {
    unsigned w = qw[threadIdx.x & 63];
    unsigned t = (w >> 8) & 0x7F;
    bool hit = (t >= 0x3Bu) && (t <= 0x42u);
    unsigned long long m = __ballot(hit);
    return __popcll(m) >= 32;
}

// ---- MFMA GEMM ----------------------------------------------------------
// C[M,N] = (A1 (+A2))[M,256] @ W[N,256]^T + bias[N] (+ Res[M,N]).
// Block 256 thr = 4 waves; 64x64 tile; wave w -> N-slice [w*16, w*16+16).
// A staged as bf16 in LDS, row stride 264 (132 words == 4 mod 32 -> 2-way
// bank aliasing on ds_read_b128, which is free). W read per-fragment from
// global: B-operand lane n=lane&15 needs W[bn+n][k=quad*8+j] — contiguous.
template<typename AT, typename IT, typename CT, bool ADD_A2, bool ADD_RES>
__device__ __forceinline__ void mfma_gemm_body(
    const AT* __restrict__ A1, const AT* __restrict__ A2,
    const IT* __restrict__ W, const IT* __restrict__ bias,
    const IT* __restrict__ Res, CT* __restrict__ C, int M, int N)
{
    __shared__ __align__(16) unsigned short As[64 * 264];
    const int tid = threadIdx.x;
    const int bm = blockIdx.y * 64;
    const int bn = blockIdx.x * 64;

    {   // stage A(+A2) -> bf16 LDS (full K=256, no K-tiling)
        const int row = tid >> 2;
        const int kb  = (tid & 3) * 64;
        const AT* a1p = A1 + (size_t)(bm + row) * K_DIM + kb;
        const AT* a2p = ADD_A2 ? (A2 + (size_t)(bm + row) * K_DIM + kb) : (const AT*)0;
        unsigned short* dst = &As[row * 264 + kb];
        #pragma unroll
        for (int j = 0; j < 64; j += 4) {
            float4 v = ld4(a1p + j);
            if (ADD_A2) {
                float4 w2 = ld4(a2p + j);
                v.x += w2.x; v.y += w2.y; v.z += w2.z; v.w += w2.w;
            }
            *(ushort4*)(dst + j) = make_ushort4(f2b(v.x), f2b(v.y), f2b(v.z), f2b(v.w));
        }
    }
    __syncthreads();

    const int wv = tid >> 6;
    const int lane = tid & 63;
    const int n15 = lane & 15;
    const int quad = lane >> 4;

    f4v acc0 = {0.f, 0.f, 0.f, 0.f};
    f4v acc1 = acc0, acc2 = acc0, acc3 = acc0;

    const IT* Wrow = W + (size_t)(bn + wv * 16 + n15) * K_DIM;
    #pragma unroll
    for (int kk = 0; kk < 8; ++kk) {
        const int k0 = kk * 32 + quad * 8;
        s8v b = ldw8(Wrow + k0);
        s8v a0 = *(const s8v*)&As[(0 * 16 + n15) * 264 + k0];
        s8v a1 = *(const s8v*)&As[(1 * 16 + n15) * 264 + k0];
        s8v a2 = *(const s8v*)&As[(2 * 16 + n15) * 264 + k0];
        s8v a3 = *(const s8v*)&As[(3 * 16 + n15) * 264 + k0];
        acc0 = __builtin_amdgcn_mfma_f32_16x16x32_bf16(a0, b, acc0, 0, 0, 0);
        acc1 = __builtin_amdgcn_mfma_f32_16x16x32_bf16(a1, b, acc1, 0, 0, 0);
        acc2 = __builtin_amdgcn_mfma_f32_16x16x32_bf16(a2, b, acc2, 0, 0, 0);
        acc3 = __builtin_amdgcn_mfma_f32_16x16x32_bf16(a3, b, acc3, 0, 0, 0);
    }

    // C/D layout: col = lane&15, row = quad*4 + reg  [verified m89/m91]
    const int n = bn + wv * 16 + n15;
    const float bv = ld1(bias + n);
    f4v accs[4] = {acc0, acc1, acc2, acc3};
    #pragma unroll
    for (int mi = 0; mi < 4; ++mi) {
        #pragma unroll
        for (int r = 0; r < 4; ++r) {
            const int m = bm + mi * 16 + quad * 4 + r;
            float v = accs[mi][r] + bv;
            if (ADD_RES) v += ld1(Res + (size_t)m * N + n);
            st1(C + (size_t)m * N + n, v);
        }
    }
}

template<bool ADD_A2>
__global__ __launch_bounds__(256) void k_gemm_in(
    const unsigned* __restrict__ qd, const void* A1, const void* A2,
    const void* W, const void* bias, bf16* C, int M, int N)
{
    if (detect_bf16(qd))
        mfma_gemm_body<bf16, bf16, bf16, ADD_A2, false>((const bf16*)A1, (const bf16*)A2,
            (const bf16*)W, (const bf16*)bias, nullptr, C, M, N);
    else
        mfma_gemm_body<float, float, bf16, ADD_A2, false>((const float*)A1, (const float*)A2,
            (const float*)W, (const float*)bias, nullptr, C, M, N);
}

__global__ __launch_bounds__(256) void k_gemm_final(
    const unsigned* __restrict__ qd, const bf16* A1,
    const void* W, const void* bias, const void* Res, void* C, int M, int N)
{
    if (detect_bf16(qd))
        mfma_gemm_body<bf16, bf16, bf16, false, true>(A1, nullptr,
            (const bf16*)W, (const bf16*)bias, (const bf16*)Res, (bf16*)C, M, N);
    else
        mfma_gemm_body<bf16, float, float, false, true>(A1, nullptr,
            (const float*)W, (const float*)bias, (const float*)Res, (float*)C, M, N);
}

// ---- fast sampler -------------------------------------------------------
// Block 256 = 4 queries x 64 threads. Thread t64: h = t64>>3, 4 channels.
// Stage 1: cooperative per-tap weight/offset precompute (2 taps/thread).
// Stage 2: pure gather (ushort4 = 4 bf16 channels per load) + FMA.
// osb holds offsets on entry, sampled on exit (in-place, block-local rows).
template<typename IT, bool HAS_LOGITS>
__device__ __forceinline__ void sample_fast_body(
    const bf16* __restrict__ vproj, bf16* __restrict__ osb,
    const bf16* __restrict__ logits,
    const IT* __restrict__ query, const IT* __restrict__ query_pos,
    const IT* __restrict__ W_attn, const IT* __restrict__ b_attn,
    const IT* __restrict__ refp)
{
    __shared__ float sofs[4][256];
    __shared__ float slog[4][128];
    __shared__ float sw[4][128];
    __shared__ float sref[4][8];
    __shared__ __align__(16) float    swgt[4][128][4];
    __shared__ __align__(16) unsigned sidx[4][128][4];
    __shared__ float sq[4][256];   // only used by !HAS_LOGITS fallback

    const int t = threadIdx.x;
    const int qg = t >> 6;
    const int t64 = t & 63;
    const int q = blockIdx.x * 4 + qg;

    {   // stage this query's offsets (bf16 x4)
        ushort4 u = *(const ushort4*)(osb + (size_t)q * 256 + t64 * 4);
        sofs[qg][t64 * 4 + 0] = b2f(u.x);
        sofs[qg][t64 * 4 + 1] = b2f(u.y);
        sofs[qg][t64 * 4 + 2] = b2f(u.z);
        sofs[qg][t64 * 4 + 3] = b2f(u.w);
    }
    if (t64 < 8) sref[qg][t64] = ld1(refp + (size_t)q * 8 + t64);

    if (HAS_LOGITS) {
        slog[qg][t64]      = ld1(logits + (size_t)q * 128 + t64);
        slog[qg][t64 + 64] = ld1(logits + (size_t)q * 128 + t64 + 64);
        __syncthreads();
    } else {
        float4 a = ld4(query + (size_t)q * 256 + t64 * 4);
        float4 b = ld4(query_pos + (size_t)q * 256 + t64 * 4);
        sq[qg][t64 * 4 + 0] = a.x + b.x;
        sq[qg][t64 * 4 + 1] = a.y + b.y;
        sq[qg][t64 * 4 + 2] = a.z + b.z;
        sq[qg][t64 * 4 + 3] = a.w + b.w;
        __syncthreads();
        #pragma unroll
        for (int c2 = 0; c2 < 2; ++c2) {
            const int c = c2 * 64 + t64;
            float acc = 0.f;
            for (int k = 0; k < 256; ++k)
                acc = fmaf(sq[qg][k], ld1(W_attn + (size_t)c * 256 + k), acc);
            slog[qg][c] = acc + ld1(b_attn + c);
        }
        __syncthreads();
    }

    if (t64 < 8) {   // per-head softmax over 16
        float m = -1e30f;
        #pragma unroll
        for (int i = 0; i < 16; ++i) m = fmaxf(m, slog[qg][t64 * 16 + i]);
        float e[16];
        float s = 0.f;
        #pragma unroll
        for (int i = 0; i < 16; ++i) { e[i] = __expf(slog[qg][t64 * 16 + i] - m); s += e[i]; }
        const float inv = 1.f / s;
        #pragma unroll
        for (int i = 0; i < 16; ++i) sw[qg][t64 * 16 + i] = e[i] * inv;
    }
    __syncthreads();

    // tap precompute: tap = h*16 + l*4 + p; stored at slot = (tap&15)*8 + h
    // (slot swizzle -> conflict-free b128 LDS reads in the gather loop)
    #pragma unroll
    for (int tt = 0; tt < 2; ++tt) {
        const int tap = t64 * 2 + tt;
        const int h = tap >> 4;
        const int l = (tap >> 2) & 3;
        const int p = tap & 3;
        const int WW = 128 >> l;                       // 128,64,32,16 (square)
        const int st = (l == 0) ? 0 : (l == 1) ? 16384 : (l == 2) ? 20480 : 21504;
        const float ox = sofs[qg][h * 32 + l * 8 + p * 2 + 0];
        const float oy = sofs[qg][h * 32 + l * 8 + p * 2 + 1];
        const float gx = sref[qg][l * 2 + 0] * (float)WW + ox - 0.5f;
        const float gy = sref[qg][l * 2 + 1] * (float)WW + oy - 0.5f;
        const float x0f = floorf(gx);
        const float y0f = floorf(gy);
        const float wx = gx - x0f;
        const float wy = gy - y0f;
        const int x0 = (int)x0f;
        const int y0 = (int)y0f;
        const float aw = sw[qg][tap];
        const float vx0 = (x0 >= 0 && x0 < WW) ? 1.f : 0.f;
        const float vx1 = (x0 + 1 >= 0 && x0 + 1 < WW) ? 1.f : 0.f;
        const float vy0 = (y0 >= 0 && y0 < WW) ? 1.f : 0.f;
        const float vy1 = (y0 + 1 >= 0 && y0 + 1 < WW) ? 1.f : 0.f;
        const int xc0 = min(max(x0, 0), WW - 1);
        const int xc1 = min(max(x0 + 1, 0), WW - 1);
        const int yc0 = min(max(y0, 0), WW - 1);
        const int yc1 = min(max(y0 + 1, 0), WW - 1);
        const int slot = ((tap & 15) << 3) | h;
        swgt[qg][slot][0] = (1.f - wx) * (1.f - wy) * aw * vx0 * vy0;
        swgt[qg][slot][1] = wx * (1.f - wy) * aw * vx1 * vy0;
        swgt[qg][slot][2] = (1.f - wx) * wy * aw * vx0 * vy1;
        swgt[qg][slot][3] = wx * wy * aw * vx1 * vy1;
        sidx[qg][slot][0] = (unsigned)(st + yc0 * WW + xc0) * 512u;
        sidx[qg][slot][1] = (unsigned)(st + yc0 * WW + xc1) * 512u;
        sidx[qg][slot][2] = (unsigned)(st + yc1 * WW + xc0) * 512u;
        sidx[qg][slot][3] = (unsigned)(st + yc1 * WW + xc1) * 512u;
    }
    __syncthreads();

    // gather: 4 channels per thread, 8-B loads
    const int h = t64 >> 3;
    const int dg = t64 & 7;
    const unsigned chb = (unsigned)(h * 32 + dg * 4) * 2u;
    const char* vb = (const char*)vproj;
    float a0 = 0.f, a1 = 0.f, a2 = 0.f, a3 = 0.f;
    #pragma unroll
    for (int i = 0; i < 16; ++i) {
        const int slot = (i << 3) | h;
        const uint4  iv = *(const uint4*)sidx[qg][slot];
        const float4 wv = *(const float4*)swgt[qg][slot];
        {
            ushort4 pv = *(const ushort4*)(vb + (size_t)(iv.x + chb));
            a0 = fmaf(wv.x, b2f(pv.x), a0); a1 = fmaf(wv.x, b2f(pv.y), a1);
            a2 = fmaf(wv.x, b2f(pv.z), a2); a3 = fmaf(wv.x, b2f(pv.w), a3);
        }
        {
            ushort4 pv = *(const ushort4*)(vb + (size_t)(iv.y + chb));
            a0 = fmaf(wv.y, b2f(pv.x), a0); a1 = fmaf(wv.y, b2f(pv.y), a1);
            a2 = fmaf(wv.y, b2f(pv.z), a2); a3 = fmaf(wv.y, b2f(pv.w), a3);
        }
        {
            ushort4 pv = *(const ushort4*)(vb + (size_t)(iv.z + chb));
            a0 = fmaf(wv.z, b2f(pv.x), a0); a1 = fmaf(wv.z, b2f(pv.y), a1);
            a2 = fmaf(wv.z, b2f(pv.z), a2); a3 = fmaf(wv.z, b2f(pv.w), a3);
        }
        {
            ushort4 pv = *(const ushort4*)(vb + (size_t)(iv.w + chb));
            a0 = fmaf(wv.w, b2f(pv.x), a0); a1 = fmaf(wv.w, b2f(pv.y), a1);
            a2 = fmaf(wv.w, b2f(pv.z), a2); a3 = fmaf(wv.w, b2f(pv.w), a3);
        }
    }
    *(ushort4*)(osb + (size_t)q * 256 + h * 32 + dg * 4) =
        make_ushort4(f2b(a0), f2b(a1), f2b(a2), f2b(a3));
}

template<bool HAS_LOGITS>
__global__ __launch_bounds__(256) void k_sample_fast(
    const unsigned* __restrict__ qd, const bf16* vproj, bf16* osb,
    const bf16* logits, const void* query, const void* query_pos,
    const void* W_attn, const void* b_attn, const void* refp)
{
    if (detect_bf16(qd))
        sample_fast_body<bf16, HAS_LOGITS>(vproj, osb, logits,
            (const bf16*)query, (const bf16*)query_pos, (const bf16*)W_attn,
            (const bf16*)b_attn, (const bf16*)refp);
    else
        sample_fast_body<float, HAS_LOGITS>(vproj, osb, logits,
            (const float*)query, (const float*)query_pos, (const float*)W_attn,
            (const float*)b_attn, (const float*)refp);
}

extern "C" void kernel_launch(void* const* d_in, const int* in_sizes, int n_in,
                              void* d_out, int out_size, void* d_ws, size_t ws_size,
                              hipStream_t stream) {
    const void* query     = d_in[0];
    const void* query_pos = d_in[1];
    const void* value     = d_in[2];
    const void* refp      = d_in[3];
    const void* W_value = d_in[5];
    const void* b_value = d_in[6];
    const void* W_off   = d_in[7];
    const void* b_off   = d_in[8];
    const void* W_attn  = d_in[9];
    const void* b_attn  = d_in[10];
    const void* W_out   = d_in[11];
    const void* b_out   = d_in[12];
    const unsigned* qd = (const unsigned*)d_in[0];

    const int M = in_sizes[0] / 256;   // 21760 = 64*340 = 4*5440
    char* wsb = (char*)d_ws;

    // bf16 workspace: vproj | osb (offsets->sampled in-place) | logits
    bf16* vproj = (bf16*)wsb;
    bf16* osb   = (bf16*)(wsb + (size_t)M * 512);
    bf16* logit = (bf16*)(wsb + (size_t)M * 1024);
    const bool sep_attn = ws_size >= (size_t)M * 1280;

    dim3 blk(256, 1, 1);
    dim3 gv(4, M / 64, 1);
    dim3 ga(2, M / 64, 1);
    dim3 gs((unsigned)(M / 4), 1, 1);

    k_gemm_in<false><<<gv, blk, 0, stream>>>(qd, value, nullptr, W_value, b_value, vproj, M, 256);
    k_gemm_in<true><<<gv, blk, 0, stream>>>(qd, query, query_pos, W_off, b_off, osb, M, 256);
    if (sep_attn) {
        k_gemm_in<true><<<ga, blk, 0, stream>>>(qd, query, query_pos, W_attn, b_attn, logit, M, 128);
        k_sample_fast<true><<<gs, blk, 0, stream>>>(qd, vproj, osb, logit, query, query_pos, W_attn, b_attn, refp);
    } else {
        k_sample_fast<false><<<gs, blk, 0, stream>>>(qd, vproj, osb, nullptr, query, query_pos, W_attn, b_attn, refp);
    }
    k_gemm_final<<<gv, blk, 0, stream>>>(qd, osb, W_out, b_out, query, d_out, M, 256);
}

// Round 9
// 276.513 us; speedup vs baseline: 2.0276x; 1.0748x over previous
//
#include <hip/hip_runtime.h>
#include <hip/hip_bf16.h>
#include <math.h>
#include <type_traits>

#define K_DIM 256
using bf16 = __hip_bfloat16;

typedef __attribute__((ext_vector_type(8))) short s8v;   // 8 bf16 (4 VGPRs)
typedef __attribute__((ext_vector_type(4))) float f4v;   // 4 f32 acc

// ---- dtype helpers ------------------------------------------------------
__device__ __forceinline__ float b2f(unsigned short u) {
    return __uint_as_float(((unsigned)u) << 16);
}
__device__ __forceinline__ unsigned short f2b(float f) {   // RNE f32->bf16
    unsigned u = __float_as_uint(f);
    unsigned r = 0x7FFFu + ((u >> 16) & 1u);
    return (unsigned short)((u + r) >> 16);
}
__device__ __forceinline__ float  ld1(const float* p) { return *p; }
__device__ __forceinline__ float  ld1(const bf16*  p) { return b2f(*(const unsigned short*)p); }
__device__ __forceinline__ void   st1(float* p, float v) { *p = v; }
__device__ __forceinline__ void   st1(bf16*  p, float v) { *(unsigned short*)p = f2b(v); }
__device__ __forceinline__ float4 ld4(const float* p) { return *(const float4*)p; }
__device__ __forceinline__ float4 ld4(const bf16*  p) {
    ushort4 u = *(const ushort4*)p;
    return make_float4(b2f(u.x), b2f(u.y), b2f(u.z), b2f(u.w));
}
__device__ __forceinline__ s8v ldw8(const bf16* p) { return *(const s8v*)p; }
__device__ __forceinline__ s8v ldw8(const float* p) {
    float4 a = *(const float4*)p;
    float4 b = *(const float4*)(p + 4);
    s8v r;
    r[0] = (short)f2b(a.x); r[1] = (short)f2b(a.y); r[2] = (short)f2b(a.z); r[3] = (short)f2b(a.w);
    r[4] = (short)f2b(b.x); r[5] = (short)f2b(b.y); r[6] = (short)f2b(b.z); r[7] = (short)f2b(b.w);
    return r;
}

// ---- runtime dtype detection (insurance) --------------------------------
__device__ __forceinline__ bool detect_bf16(const unsigned* __restrict__ qw) {
    unsigned w = qw[threadIdx.x & 63];
    unsigned t = (w >> 8) & 0x7F;
    bool hit = (t >= 0x3Bu) && (t <= 0x42u);
    unsigned long long m = __ballot(hit);
    return __popcll(m) >= 32;
}

// ---- MFMA GEMM ----------------------------------------------------------
// Block = 4 waves, full-N row-tile: 64 rows x (4*NFRAG*16) cols, K=256.
// A(+A2) staged ONCE as bf16 in LDS (stride 264 -> 2-way alias, free).
// Wave wv covers cols [wv*NFRAG*16, ...). B frag read direct from global
// (lane n=lane&15 reads W[col][k0..k0+8] -- contiguous, L2/L3-hot).
// SPLIT: cols >= N1 route to W2/bias2/C2 (fused offs+attn GEMM).
template<typename AT, typename IT, typename CT, int NFRAG, bool ADD_A2, bool SPLIT, bool ADD_RES>
__device__ __forceinline__ void mfma_gemm_body(
    unsigned short* __restrict__ As,
    const AT* __restrict__ A1, const AT* __restrict__ A2,
    const IT* __restrict__ W1, const IT* __restrict__ bias1, CT* __restrict__ C1, int N1,
    const IT* __restrict__ W2, const IT* __restrict__ bias2, CT* __restrict__ C2, int N2,
    const IT* __restrict__ Res)
{
    const int tid = threadIdx.x;
    const int bm = blockIdx.x * 64;

    {   // stage A(+A2) -> bf16 LDS, full K
        const int row = tid >> 2;
        const int kb  = (tid & 3) * 64;
        unsigned short* dst = &As[row * 264 + kb];
        const AT* a1p = A1 + (size_t)(bm + row) * K_DIM + kb;
        if constexpr (!ADD_A2 && std::is_same<AT, bf16>::value) {
            #pragma unroll
            for (int j = 0; j < 64; j += 8)
                *(s8v*)(dst + j) = *(const s8v*)(a1p + j);
        } else {
            const AT* a2p = ADD_A2 ? (A2 + (size_t)(bm + row) * K_DIM + kb) : (const AT*)0;
            #pragma unroll
            for (int j = 0; j < 64; j += 4) {
                float4 v = ld4(a1p + j);
                if (ADD_A2) {
                    float4 w2 = ld4(a2p + j);
                    v.x += w2.x; v.y += w2.y; v.z += w2.z; v.w += w2.w;
                }
                *(ushort4*)(dst + j) = make_ushort4(f2b(v.x), f2b(v.y), f2b(v.z), f2b(v.w));
            }
        }
    }
    __syncthreads();

    const int wv = tid >> 6;
    const int lane = tid & 63;
    const int n15 = lane & 15;
    const int quad = lane >> 4;

    const IT* Wr[NFRAG];
    int col[NFRAG];
    #pragma unroll
    for (int f = 0; f < NFRAG; ++f) {
        const int c = (wv * NFRAG + f) * 16 + n15;
        col[f] = c;
        if (SPLIT && c >= N1) Wr[f] = W2 + (size_t)(c - N1) * K_DIM;
        else                  Wr[f] = W1 + (size_t)c * K_DIM;
    }

    const f4v zz = {0.f, 0.f, 0.f, 0.f};
    f4v acc[4][NFRAG];
    #pragma unroll
    for (int mi = 0; mi < 4; ++mi)
        #pragma unroll
        for (int f = 0; f < NFRAG; ++f) acc[mi][f] = zz;

    #pragma unroll
    for (int kk = 0; kk < 8; ++kk) {
        const int k0 = kk * 32 + quad * 8;
        s8v b[NFRAG];
        #pragma unroll
        for (int f = 0; f < NFRAG; ++f) b[f] = ldw8(Wr[f] + k0);
        s8v a[4];
        #pragma unroll
        for (int mi = 0; mi < 4; ++mi)
            a[mi] = *(const s8v*)&As[(mi * 16 + n15) * 264 + k0];
        #pragma unroll
        for (int mi = 0; mi < 4; ++mi)
            #pragma unroll
            for (int f = 0; f < NFRAG; ++f)
                acc[mi][f] = __builtin_amdgcn_mfma_f32_16x16x32_bf16(a[mi], b[f], acc[mi][f], 0, 0, 0);
    }

    // C/D: col = lane&15, row = quad*4 + reg  [verified working r7/r8]
    #pragma unroll
    for (int f = 0; f < NFRAG; ++f) {
        const int c = col[f];
        const bool hi = SPLIT && (c >= N1);
        const float bv = hi ? ld1(bias2 + (c - N1)) : ld1(bias1 + c);
        #pragma unroll
        for (int mi = 0; mi < 4; ++mi)
            #pragma unroll
            for (int r = 0; r < 4; ++r) {
                const int m = bm + mi * 16 + quad * 4 + r;
                float v = acc[mi][f][r] + bv;
                if (ADD_RES) v += ld1(Res + (size_t)m * N1 + c);
                if (hi) st1(C2 + (size_t)m * N2 + (c - N1), v);
                else    st1(C1 + (size_t)m * N1 + c, v);
            }
    }
}

// Input-typed GEMM -> bf16 intermediates (optionally split outputs).
template<int NFRAG, bool ADD_A2, bool SPLIT>
__global__ __launch_bounds__(256) void k_gemm(
    const unsigned* __restrict__ qd, const void* A1, const void* A2,
    const void* W1, const void* b1, bf16* C1, int N1,
    const void* W2, const void* b2, bf16* C2, int N2)
{
    __shared__ unsigned short As[64 * 264];
    if (detect_bf16(qd))
        mfma_gemm_body<bf16, bf16, bf16, NFRAG, ADD_A2, SPLIT, false>(As,
            (const bf16*)A1, (const bf16*)A2, (const bf16*)W1, (const bf16*)b1, C1, N1,
            (const bf16*)W2, (const bf16*)b2, C2, N2, nullptr);
    else
        mfma_gemm_body<float, float, bf16, NFRAG, ADD_A2, SPLIT, false>(As,
            (const float*)A1, (const float*)A2, (const float*)W1, (const float*)b1, C1, N1,
            (const float*)W2, (const float*)b2, C2, N2, nullptr);
}

// Final GEMM: bf16 A (sampled), input-typed W/bias/Res, input-typed d_out.
__global__ __launch_bounds__(256) void k_gemm_final(
    const unsigned* __restrict__ qd, const bf16* A1,
    const void* W, const void* bias, const void* Res, void* C)
{
    __shared__ unsigned short As[64 * 264];
    if (detect_bf16(qd))
        mfma_gemm_body<bf16, bf16, bf16, 4, false, false, true>(As,
            A1, nullptr, (const bf16*)W, (const bf16*)bias, (bf16*)C, 256,
            nullptr, nullptr, nullptr, 0, (const bf16*)Res);
    else
        mfma_gemm_body<bf16, float, float, 4, false, false, true>(As,
            A1, nullptr, (const float*)W, (const float*)bias, (float*)C, 256,
            nullptr, nullptr, nullptr, 0, (const float*)Res);
}

// ---- fast sampler -------------------------------------------------------
struct SampLds {
    float    sofs[4][256];
    float    slog[4][128];
    float    sw[4][128];
    float    sref[4][8];
    float    swgt[4][128][4];
    unsigned sidx[4][128][4];
};   // 24704 B

template<typename IT, bool HAS_LOGITS>
__device__ __forceinline__ void sample_fast_body(
    SampLds& L, float (*sq)[256],
    const bf16* __restrict__ vproj, bf16* __restrict__ osb,
    const bf16* __restrict__ logits,
    const IT* __restrict__ query, const IT* __restrict__ query_pos,
    const IT* __restrict__ W_attn, const IT* __restrict__ b_attn,
    const IT* __restrict__ refp)
{
    const int t = threadIdx.x;
    const int qg = t >> 6;
    const int t64 = t & 63;
    const int q = blockIdx.x * 4 + qg;

    {   // stage this query's offsets (bf16 x4 -> float4 LDS store)
        ushort4 u = *(const ushort4*)(osb + (size_t)q * 256 + t64 * 4);
        *(float4*)&L.sofs[qg][t64 * 4] = make_float4(b2f(u.x), b2f(u.y), b2f(u.z), b2f(u.w));
    }
    if (t64 < 8) L.sref[qg][t64] = ld1(refp + (size_t)q * 8 + t64);

    if (HAS_LOGITS) {
        L.slog[qg][t64]      = ld1(logits + (size_t)q * 128 + t64);
        L.slog[qg][t64 + 64] = ld1(logits + (size_t)q * 128 + t64 + 64);
        __syncthreads();
    } else {
        float4 a = ld4(query + (size_t)q * 256 + t64 * 4);
        float4 b = ld4(query_pos + (size_t)q * 256 + t64 * 4);
        *(float4*)&sq[qg][t64 * 4] = make_float4(a.x + b.x, a.y + b.y, a.z + b.z, a.w + b.w);
        __syncthreads();
        #pragma unroll
        for (int c2 = 0; c2 < 2; ++c2) {
            const int c = c2 * 64 + t64;
            float acc = 0.f;
            for (int k = 0; k < 256; ++k)
                acc = fmaf(sq[qg][k], ld1(W_attn + (size_t)c * 256 + k), acc);
            L.slog[qg][c] = acc + ld1(b_attn + c);
        }
        __syncthreads();
    }

    if (t64 < 8) {   // per-head softmax over 16
        float m = -1e30f;
        #pragma unroll
        for (int i = 0; i < 16; ++i) m = fmaxf(m, L.slog[qg][t64 * 16 + i]);
        float e[16];
        float s = 0.f;
        #pragma unroll
        for (int i = 0; i < 16; ++i) { e[i] = __expf(L.slog[qg][t64 * 16 + i] - m); s += e[i]; }
        const float inv = 1.f / s;
        #pragma unroll
        for (int i = 0; i < 16; ++i) L.sw[qg][t64 * 16 + i] = e[i] * inv;
    }
    __syncthreads();

    // tap precompute. Thread t64: h = t64&7, i-pair = t64>>3 -> consecutive
    // lanes write consecutive slots (b128, conflict-free). slot = i*8+h so
    // the gather loop's 8 h-readers land on distinct bank groups.
    {
        const int hh = t64 & 7;
        const int i2 = t64 >> 3;
        #pragma unroll
        for (int tt = 0; tt < 2; ++tt) {
            const int i = i2 * 2 + tt;             // (l,p) index in [0,16)
            const int l = i >> 2;
            const int p = i & 3;
            const int WW = 128 >> l;
            const int st = (l == 0) ? 0 : (l == 1) ? 16384 : (l == 2) ? 20480 : 21504;
            const float ox = L.sofs[qg][hh * 32 + l * 8 + p * 2 + 0];
            const float oy = L.sofs[qg][hh * 32 + l * 8 + p * 2 + 1];
            const float gx = L.sref[qg][l * 2 + 0] * (float)WW + ox - 0.5f;
            const float gy = L.sref[qg][l * 2 + 1] * (float)WW + oy - 0.5f;
            const float x0f = floorf(gx);
            const float y0f = floorf(gy);
            const float wx = gx - x0f;
            const float wy = gy - y0f;
            const int x0 = (int)x0f;
            const int y0 = (int)y0f;
            const float aw = L.sw[qg][hh * 16 + i];
            const float vx0 = (x0 >= 0 && x0 < WW) ? 1.f : 0.f;
            const float vx1 = (x0 + 1 >= 0 && x0 + 1 < WW) ? 1.f : 0.f;
            const float vy0 = (y0 >= 0 && y0 < WW) ? 1.f : 0.f;
            const float vy1 = (y0 + 1 >= 0 && y0 + 1 < WW) ? 1.f : 0.f;
            const int xc0 = min(max(x0, 0), WW - 1);
            const int xc1 = min(max(x0 + 1, 0), WW - 1);
            const int yc0 = min(max(y0, 0), WW - 1);
            const int yc1 = min(max(y0 + 1, 0), WW - 1);
            const int slot = i * 8 + hh;
            *(float4*)L.swgt[qg][slot] = make_float4(
                (1.f - wx) * (1.f - wy) * aw * vx0 * vy0,
                wx * (1.f - wy) * aw * vx1 * vy0,
                (1.f - wx) * wy * aw * vx0 * vy1,
                wx * wy * aw * vx1 * vy1);
            *(uint4*)L.sidx[qg][slot] = make_uint4(
                (unsigned)(st + yc0 * WW + xc0) * 512u,
                (unsigned)(st + yc0 * WW + xc1) * 512u,
                (unsigned)(st + yc1 * WW + xc0) * 512u,
                (unsigned)(st + yc1 * WW + xc1) * 512u);
        }
    }
    __syncthreads();

    // gather: 4 channels/thread, ushort4 loads
    const int h = t64 >> 3;
    const int dg = t64 & 7;
    const unsigned chb = (unsigned)(h * 32 + dg * 4) * 2u;
    const char* vb = (const char*)vproj;
    float a0 = 0.f, a1 = 0.f, a2 = 0.f, a3 = 0.f;
    #pragma unroll
    for (int i = 0; i < 16; ++i) {
        const int slot = (i << 3) | h;
        const uint4  iv = *(const uint4*)L.sidx[qg][slot];
        const float4 wv = *(const float4*)L.swgt[qg][slot];
        {
            ushort4 pv = *(const ushort4*)(vb + (size_t)(iv.x + chb));
            a0 = fmaf(wv.x, b2f(pv.x), a0); a1 = fmaf(wv.x, b2f(pv.y), a1);
            a2 = fmaf(wv.x, b2f(pv.z), a2); a3 = fmaf(wv.x, b2f(pv.w), a3);
        }
        {
            ushort4 pv = *(const ushort4*)(vb + (size_t)(iv.y + chb));
            a0 = fmaf(wv.y, b2f(pv.x), a0); a1 = fmaf(wv.y, b2f(pv.y), a1);
            a2 = fmaf(wv.y, b2f(pv.z), a2); a3 = fmaf(wv.y, b2f(pv.w), a3);
        }
        {
            ushort4 pv = *(const ushort4*)(vb + (size_t)(iv.z + chb));
            a0 = fmaf(wv.z, b2f(pv.x), a0); a1 = fmaf(wv.z, b2f(pv.y), a1);
            a2 = fmaf(wv.z, b2f(pv.z), a2); a3 = fmaf(wv.z, b2f(pv.w), a3);
        }
        {
            ushort4 pv = *(const ushort4*)(vb + (size_t)(iv.w + chb));
            a0 = fmaf(wv.w, b2f(pv.x), a0); a1 = fmaf(wv.w, b2f(pv.y), a1);
            a2 = fmaf(wv.w, b2f(pv.z), a2); a3 = fmaf(wv.w, b2f(pv.w), a3);
        }
    }
    *(ushort4*)(osb + (size_t)q * 256 + h * 32 + dg * 4) =
        make_ushort4(f2b(a0), f2b(a1), f2b(a2), f2b(a3));
}

template<bool HAS_LOGITS>
__global__ __launch_bounds__(256) void k_sample_fast(
    const unsigned* __restrict__ qd, const bf16* vproj, bf16* osb,
    const bf16* logits, const void* query, const void* query_pos,
    const void* W_attn, const void* b_attn, const void* refp)
{
    __shared__ SampLds L;
    if constexpr (HAS_LOGITS) {
        if (detect_bf16(qd))
            sample_fast_body<bf16, true>(L, nullptr, vproj, osb, logits,
                (const bf16*)query, (const bf16*)query_pos, (const bf16*)W_attn,
                (const bf16*)b_attn, (const bf16*)refp);
        else
            sample_fast_body<float, true>(L, nullptr, vproj, osb, logits,
                (const float*)query, (const float*)query_pos, (const float*)W_attn,
                (const float*)b_attn, (const float*)refp);
    } else {
        __shared__ float sq[4][256];
        if (detect_bf16(qd))
            sample_fast_body<bf16, false>(L, sq, vproj, osb, logits,
                (const bf16*)query, (const bf16*)query_pos, (const bf16*)W_attn,
                (const bf16*)b_attn, (const bf16*)refp);
        else
            sample_fast_body<float, false>(L, sq, vproj, osb, logits,
                (const float*)query, (const float*)query_pos, (const float*)W_attn,
                (const float*)b_attn, (const float*)refp);
    }
}

extern "C" void kernel_launch(void* const* d_in, const int* in_sizes, int n_in,
                              void* d_out, int out_size, void* d_ws, size_t ws_size,
                              hipStream_t stream) {
    const void* query     = d_in[0];
    const void* query_pos = d_in[1];
    const void* value     = d_in[2];
    const void* refp      = d_in[3];
    const void* W_value = d_in[5];
    const void* b_value = d_in[6];
    const void* W_off   = d_in[7];
    const void* b_off   = d_in[8];
    const void* W_attn  = d_in[9];
    const void* b_attn  = d_in[10];
    const void* W_out   = d_in[11];
    const void* b_out   = d_in[12];
    const unsigned* qd = (const unsigned*)d_in[0];

    const int M = in_sizes[0] / 256;   // 21760 = 64*340 = 4*5440
    char* wsb = (char*)d_ws;

    bf16* vproj = (bf16*)wsb;                        // M*512 B
    bf16* osb   = (bf16*)(wsb + (size_t)M * 512);    // M*512 B
    bf16* logit = (bf16*)(wsb + (size_t)M * 1024);   // M*256 B
    const bool sep_attn = ws_size >= (size_t)M * 1280;

    dim3 blk(256, 1, 1);
    dim3 g64((unsigned)(M / 64), 1, 1);   // 340 row-tiles, full N per block
    dim3 gs((unsigned)(M / 4), 1, 1);

    // v = value @ W_value^T + b_value -> vproj (bf16), N=256
    k_gemm<4, false, false><<<g64, blk, 0, stream>>>(qd, value, nullptr,
        W_value, b_value, vproj, 256, nullptr, nullptr, nullptr, 0);
    if (sep_attn) {
        // fused: (q+qp) @ [W_off; W_attn]^T -> osb (256) | logit (128)
        k_gemm<6, true, true><<<g64, blk, 0, stream>>>(qd, query, query_pos,
            W_off, b_off, osb, 256, W_attn, b_attn, logit, 128);
        k_sample_fast<true><<<gs, blk, 0, stream>>>(qd, vproj, osb, logit,
            query, query_pos, W_attn, b_attn, refp);
    } else {
        k_gemm<4, true, false><<<g64, blk, 0, stream>>>(qd, query, query_pos,
            W_off, b_off, osb, 256, nullptr, nullptr, nullptr, 0);
        k_sample_fast<false><<<gs, blk, 0, stream>>>(qd, vproj, osb, nullptr,
            query, query_pos, W_attn, b_attn, refp);
    }
    // out = sampled @ W_out^T + b_out + query -> d_out (input dtype)
    k_gemm_final<<<g64, blk, 0, stream>>>(qd, osb, W_out, b_out, query, d_out);
}

// Round 10
// 274.474 us; speedup vs baseline: 2.0427x; 1.0074x over previous
//
#include <hip/hip_runtime.h>
#include <hip/hip_bf16.h>
#include <math.h>
#include <type_traits>

#define K_DIM 256
using bf16 = __hip_bfloat16;

typedef __attribute__((ext_vector_type(8))) short s8v;   // 8 bf16 (4 VGPRs)
typedef __attribute__((ext_vector_type(4))) float f4v;   // 4 f32 acc

// ---- dtype helpers ------------------------------------------------------
__device__ __forceinline__ float b2f(unsigned short u) {
    return __uint_as_float(((unsigned)u) << 16);
}
__device__ __forceinline__ unsigned short f2b(float f) {   // RNE f32->bf16
    unsigned u = __float_as_uint(f);
    unsigned r = 0x7FFFu + ((u >> 16) & 1u);
    return (unsigned short)((u + r) >> 16);
}
__device__ __forceinline__ float  ld1(const float* p) { return *p; }
__device__ __forceinline__ float  ld1(const bf16*  p) { return b2f(*(const unsigned short*)p); }
__device__ __forceinline__ void   st1(float* p, float v) { *p = v; }
__device__ __forceinline__ void   st1(bf16*  p, float v) { *(unsigned short*)p = f2b(v); }
__device__ __forceinline__ float4 ld4(const float* p) { return *(const float4*)p; }
__device__ __forceinline__ float4 ld4(const bf16*  p) {
    ushort4 u = *(const ushort4*)p;
    return make_float4(b2f(u.x), b2f(u.y), b2f(u.z), b2f(u.w));
}
__device__ __forceinline__ s8v ldw8(const bf16* p) { return *(const s8v*)p; }
__device__ __forceinline__ s8v ldw8(const float* p) {
    float4 a = *(const float4*)p;
    float4 b = *(const float4*)(p + 4);
    s8v r;
    r[0] = (short)f2b(a.x); r[1] = (short)f2b(a.y); r[2] = (short)f2b(a.z); r[3] = (short)f2b(a.w);
    r[4] = (short)f2b(b.x); r[5] = (short)f2b(b.y); r[6] = (short)f2b(b.z); r[7] = (short)f2b(b.w);
    return r;
}

// ---- runtime dtype detection (insurance; evidence says f32) -------------
__device__ __forceinline__ bool detect_bf16(const unsigned* __restrict__ qw) {
    unsigned w = qw[threadIdx.x & 63];
    unsigned t = (w >> 8) & 0x7F;
    bool hit = (t >= 0x3Bu) && (t <= 0x42u);
    unsigned long long m = __ballot(hit);
    return __popcll(m) >= 32;
}

// ---- MFMA GEMM ----------------------------------------------------------
// 32-row tiles (grid M/32=680), full N per block, K=256.
// A-tile (32 x 256) is CONTIGUOUS in memory -> staged with flat coalesced
// loads (lane-consecutive 16B/8B chunks), row/col decoded arithmetically.
// LDS stride 264 elems. B frags read direct from global (L2-hot).
// SPLIT: cols >= N1 route to W2/bias2/C2(bf16) (fused offs+attn; C2=d_out scratch).
template<typename AT, typename IT, typename CT, int NFRAG, bool ADD_A2, bool SPLIT, bool ADD_RES>
__device__ __forceinline__ void mfma_gemm_body(
    unsigned short* __restrict__ As,
    const AT* __restrict__ A1, const AT* __restrict__ A2,
    const IT* __restrict__ W1, const IT* __restrict__ bias1, CT* __restrict__ C1, int N1,
    const IT* __restrict__ W2, const IT* __restrict__ bias2, bf16* __restrict__ C2, int N2,
    const IT* __restrict__ Res)
{
    const int tid = threadIdx.x;
    const int bm = blockIdx.x * 32;

    {   // stage A(+A2) -> bf16 LDS; tile is contiguous: coalesced flat loads
        const AT* t1 = A1 + (size_t)bm * K_DIM;
        if constexpr (!ADD_A2 && std::is_same<AT, bf16>::value) {
            #pragma unroll
            for (int j = 0; j < 4; ++j) {           // 2048 elems/iter, 16B/lane
                const int e = j * 2048 + tid * 8;
                const int row = e >> 8, col = e & 255;
                *(s8v*)&As[row * 264 + col] = *(const s8v*)(t1 + e);
            }
        } else {
            const AT* t2 = ADD_A2 ? (A2 + (size_t)bm * K_DIM) : (const AT*)0;
            #pragma unroll
            for (int j = 0; j < 8; ++j) {           // 1024 elems/iter, 4 elems/lane
                const int e = j * 1024 + tid * 4;
                float4 v = ld4(t1 + e);
                if (ADD_A2) {
                    float4 w2 = ld4(t2 + e);
                    v.x += w2.x; v.y += w2.y; v.z += w2.z; v.w += w2.w;
                }
                const int row = e >> 8, col = e & 255;
                *(ushort4*)&As[row * 264 + col] =
                    make_ushort4(f2b(v.x), f2b(v.y), f2b(v.z), f2b(v.w));
            }
        }
    }
    __syncthreads();

    const int wv = tid >> 6;
    const int lane = tid & 63;
    const int n15 = lane & 15;
    const int quad = lane >> 4;

    const IT* Wr[NFRAG];
    int col[NFRAG];
    #pragma unroll
    for (int f = 0; f < NFRAG; ++f) {
        const int c = (wv * NFRAG + f) * 16 + n15;
        col[f] = c;
        if (SPLIT && c >= N1) Wr[f] = W2 + (size_t)(c - N1) * K_DIM;
        else                  Wr[f] = W1 + (size_t)c * K_DIM;
    }

    const f4v zz = {0.f, 0.f, 0.f, 0.f};
    f4v acc[2][NFRAG];
    #pragma unroll
    for (int mi = 0; mi < 2; ++mi)
        #pragma unroll
        for (int f = 0; f < NFRAG; ++f) acc[mi][f] = zz;

    #pragma unroll
    for (int kk = 0; kk < 8; ++kk) {
        const int k0 = kk * 32 + quad * 8;
        s8v b[NFRAG];
        #pragma unroll
        for (int f = 0; f < NFRAG; ++f) b[f] = ldw8(Wr[f] + k0);
        s8v a[2];
        #pragma unroll
        for (int mi = 0; mi < 2; ++mi)
            a[mi] = *(const s8v*)&As[(mi * 16 + n15) * 264 + k0];
        #pragma unroll
        for (int mi = 0; mi < 2; ++mi)
            #pragma unroll
            for (int f = 0; f < NFRAG; ++f)
                acc[mi][f] = __builtin_amdgcn_mfma_f32_16x16x32_bf16(a[mi], b[f], acc[mi][f], 0, 0, 0);
    }

    // C/D: col = lane&15, row = quad*4 + reg
    #pragma unroll
    for (int f = 0; f < NFRAG; ++f) {
        const int c = col[f];
        const bool hi = SPLIT && (c >= N1);
        const float bv = hi ? ld1(bias2 + (c - N1)) : ld1(bias1 + c);
        #pragma unroll
        for (int mi = 0; mi < 2; ++mi)
            #pragma unroll
            for (int r = 0; r < 4; ++r) {
                const int m = bm + mi * 16 + quad * 4 + r;
                float v = acc[mi][f][r] + bv;
                if (ADD_RES) v += ld1(Res + (size_t)m * N1 + c);
                if (hi) st1(C2 + (size_t)m * N2 + (c - N1), v);
                else    st1(C1 + (size_t)m * N1 + c, v);
            }
    }
}

template<int NFRAG, bool ADD_A2, bool SPLIT>
__global__ __launch_bounds__(256) void k_gemm(
    const unsigned* __restrict__ qd, const void* A1, const void* A2,
    const void* W1, const void* b1, bf16* C1, int N1,
    const void* W2, const void* b2, bf16* C2, int N2)
{
    __shared__ unsigned short As[32 * 264];
    if (detect_bf16(qd))
        mfma_gemm_body<bf16, bf16, bf16, NFRAG, ADD_A2, SPLIT, false>(As,
            (const bf16*)A1, (const bf16*)A2, (const bf16*)W1, (const bf16*)b1, C1, N1,
            (const bf16*)W2, (const bf16*)b2, C2, N2, nullptr);
    else
        mfma_gemm_body<float, float, bf16, NFRAG, ADD_A2, SPLIT, false>(As,
            (const float*)A1, (const float*)A2, (const float*)W1, (const float*)b1, C1, N1,
            (const float*)W2, (const float*)b2, C2, N2, nullptr);
}

// Final GEMM: bf16 A (sampled), input-typed W/bias/Res, input-typed d_out.
__global__ __launch_bounds__(256) void k_gemm_final(
    const unsigned* __restrict__ qd, const bf16* A1,
    const void* W, const void* bias, const void* Res, void* C)
{
    __shared__ unsigned short As[32 * 264];
    if (detect_bf16(qd))
        mfma_gemm_body<bf16, bf16, bf16, 4, false, false, true>(As,
            A1, nullptr, (const bf16*)W, (const bf16*)bias, (bf16*)C, 256,
            nullptr, nullptr, nullptr, 0, (const bf16*)Res);
    else
        mfma_gemm_body<bf16, float, float, 4, false, false, true>(As,
            A1, nullptr, (const float*)W, (const float*)bias, (float*)C, 256,
            nullptr, nullptr, nullptr, 0, (const float*)Res);
}

// ---- sampler ------------------------------------------------------------
// Block 256 = 4 queries x 64 threads; logits are ALWAYS precomputed
// (staged as bf16 in d_out by the fused GEMM).
struct SampLds {
    float    sofs[4][256];
    float    slog[4][128];    // logits, softmaxed in-place
    float    sref[4][8];
    float    swgt[4][128][4];
    unsigned sidx[4][128][4];
};   // 22,656 B

__global__ __launch_bounds__(256) void k_sample(
    const unsigned* __restrict__ qd, const bf16* __restrict__ vproj,
    bf16* __restrict__ osb, const bf16* __restrict__ logits,
    const void* __restrict__ refp)
{
    __shared__ SampLds L;
    const bool isb = detect_bf16(qd);
    const int t = threadIdx.x;
    const int qg = t >> 6;
    const int t64 = t & 63;
    const int q = blockIdx.x * 4 + qg;

    {   // stage offsets (bf16 x4 -> float4 LDS)
        ushort4 u = *(const ushort4*)(osb + (size_t)q * 256 + t64 * 4);
        *(float4*)&L.sofs[qg][t64 * 4] = make_float4(b2f(u.x), b2f(u.y), b2f(u.z), b2f(u.w));
    }
    L.slog[qg][t64]      = ld1(logits + (size_t)q * 128 + t64);
    L.slog[qg][t64 + 64] = ld1(logits + (size_t)q * 128 + t64 + 64);
    if (t64 < 8)
        L.sref[qg][t64] = isb ? ld1((const bf16*)refp + (size_t)q * 8 + t64)
                              : ld1((const float*)refp + (size_t)q * 8 + t64);
    __syncthreads();

    if (t64 < 8) {   // per-head softmax over 16, in place
        float m = -1e30f;
        #pragma unroll
        for (int i = 0; i < 16; ++i) m = fmaxf(m, L.slog[qg][t64 * 16 + i]);
        float e[16];
        float s = 0.f;
        #pragma unroll
        for (int i = 0; i < 16; ++i) { e[i] = __expf(L.slog[qg][t64 * 16 + i] - m); s += e[i]; }
        const float inv = 1.f / s;
        #pragma unroll
        for (int i = 0; i < 16; ++i) L.slog[qg][t64 * 16 + i] = e[i] * inv;
    }
    __syncthreads();

    // tap precompute. Writer lane t64 -> (h = t64&7, i = 2*(t64>>3)+tt);
    // physical slot = 2*t64 + tt  => contiguous 32 B per lane (conflict-free
    // writes). Reader maps (i,h) -> 16*(i>>1) + 2*h + (i&1).
    {
        const int hh = t64 & 7;
        const int i2 = t64 >> 3;
        #pragma unroll
        for (int tt = 0; tt < 2; ++tt) {
            const int i = i2 * 2 + tt;             // (l,p) in [0,16)
            const int l = i >> 2;
            const int p = i & 3;
            const int WW = 128 >> l;
            const int st = (l == 0) ? 0 : (l == 1) ? 16384 : (l == 2) ? 20480 : 21504;
            const float ox = L.sofs[qg][hh * 32 + l * 8 + p * 2 + 0];
            const float oy = L.sofs[qg][hh * 32 + l * 8 + p * 2 + 1];
            const float gx = L.sref[qg][l * 2 + 0] * (float)WW + ox - 0.5f;
            const float gy = L.sref[qg][l * 2 + 1] * (float)WW + oy - 0.5f;
            const float x0f = floorf(gx);
            const float y0f = floorf(gy);
            const float wx = gx - x0f;
            const float wy = gy - y0f;
            const int x0 = (int)x0f;
            const int y0 = (int)y0f;
            const float aw = L.slog[qg][hh * 16 + i];
            const float vx0 = (x0 >= 0 && x0 < WW) ? 1.f : 0.f;
            const float vx1 = (x0 + 1 >= 0 && x0 + 1 < WW) ? 1.f : 0.f;
            const float vy0 = (y0 >= 0 && y0 < WW) ? 1.f : 0.f;
            const float vy1 = (y0 + 1 >= 0 && y0 + 1 < WW) ? 1.f : 0.f;
            const int xc0 = min(max(x0, 0), WW - 1);
            const int xc1 = min(max(x0 + 1, 0), WW - 1);
            const int yc0 = min(max(y0, 0), WW - 1);
            const int yc1 = min(max(y0 + 1, 0), WW - 1);
            const int slot = 2 * t64 + tt;
            *(float4*)L.swgt[qg][slot] = make_float4(
                (1.f - wx) * (1.f - wy) * aw * vx0 * vy0,
                wx * (1.f - wy) * aw * vx1 * vy0,
                (1.f - wx) * wy * aw * vx0 * vy1,
                wx * wy * aw * vx1 * vy1);
            *(uint4*)L.sidx[qg][slot] = make_uint4(
                (unsigned)(st + yc0 * WW + xc0) * 512u,
                (unsigned)(st + yc0 * WW + xc1) * 512u,
                (unsigned)(st + yc1 * WW + xc0) * 512u,
                (unsigned)(st + yc1 * WW + xc1) * 512u);
        }
    }
    __syncthreads();

    // gather: 4 channels/thread, ushort4 loads
    const int h = t64 >> 3;
    const int dg = t64 & 7;
    const unsigned chb = (unsigned)(h * 32 + dg * 4) * 2u;
    const char* vb = (const char*)vproj;
    float a0 = 0.f, a1 = 0.f, a2 = 0.f, a3 = 0.f;
    #pragma unroll
    for (int i = 0; i < 16; ++i) {
        const int slot = 16 * (i >> 1) + 2 * h + (i & 1);
        const uint4  iv = *(const uint4*)L.sidx[qg][slot];
        const float4 wv = *(const float4*)L.swgt[qg][slot];
        {
            ushort4 pv = *(const ushort4*)(vb + (size_t)(iv.x + chb));
            a0 = fmaf(wv.x, b2f(pv.x), a0); a1 = fmaf(wv.x, b2f(pv.y), a1);
            a2 = fmaf(wv.x, b2f(pv.z), a2); a3 = fmaf(wv.x, b2f(pv.w), a3);
        }
        {
            ushort4 pv = *(const ushort4*)(vb + (size_t)(iv.y + chb));
            a0 = fmaf(wv.y, b2f(pv.x), a0); a1 = fmaf(wv.y, b2f(pv.y), a1);
            a2 = fmaf(wv.y, b2f(pv.z), a2); a3 = fmaf(wv.y, b2f(pv.w), a3);
        }
        {
            ushort4 pv = *(const ushort4*)(vb + (size_t)(iv.z + chb));
            a0 = fmaf(wv.z, b2f(pv.x), a0); a1 = fmaf(wv.z, b2f(pv.y), a1);
            a2 = fmaf(wv.z, b2f(pv.z), a2); a3 = fmaf(wv.z, b2f(pv.w), a3);
        }
        {
            ushort4 pv = *(const ushort4*)(vb + (size_t)(iv.w + chb));
            a0 = fmaf(wv.w, b2f(pv.x), a0); a1 = fmaf(wv.w, b2f(pv.y), a1);
            a2 = fmaf(wv.w, b2f(pv.z), a2); a3 = fmaf(wv.w, b2f(pv.w), a3);
        }
    }
    *(ushort4*)(osb + (size_t)q * 256 + h * 32 + dg * 4) =
        make_ushort4(f2b(a0), f2b(a1), f2b(a2), f2b(a3));
}

extern "C" void kernel_launch(void* const* d_in, const int* in_sizes, int n_in,
                              void* d_out, int out_size, void* d_ws, size_t ws_size,
                              hipStream_t stream) {
    const void* query     = d_in[0];
    const void* query_pos = d_in[1];
    const void* value     = d_in[2];
    const void* refp      = d_in[3];
    const void* W_value = d_in[5];
    const void* b_value = d_in[6];
    const void* W_off   = d_in[7];
    const void* b_off   = d_in[8];
    const void* W_attn  = d_in[9];
    const void* b_attn  = d_in[10];
    const void* W_out   = d_in[11];
    const void* b_out   = d_in[12];
    const unsigned* qd = (const unsigned*)d_in[0];

    const int M = in_sizes[0] / 256;   // 21760 = 32*680 = 4*5440
    char* wsb = (char*)d_ws;

    // ws (22.3 MB budget): vproj | osb. Logits staged in d_out (bf16),
    // dead once k_gemm_final overwrites d_out.
    bf16* vproj = (bf16*)wsb;                      // M*512 B
    bf16* osb   = (bf16*)(wsb + (size_t)M * 512);  // M*512 B
    bf16* logit = (bf16*)d_out;                    // M*256 B scratch

    dim3 blk(256, 1, 1);
    dim3 g32((unsigned)(M / 32), 1, 1);   // 680 row-tiles, full N per block
    dim3 gs((unsigned)(M / 4), 1, 1);

    // v = value @ W_value^T + b_value -> vproj
    k_gemm<4, false, false><<<g32, blk, 0, stream>>>(qd, value, nullptr,
        W_value, b_value, vproj, 256, nullptr, nullptr, nullptr, 0);
    // fused: (q+qp) @ [W_off | W_attn]^T -> osb (256) | logit->d_out (128)
    k_gemm<6, true, true><<<g32, blk, 0, stream>>>(qd, query, query_pos,
        W_off, b_off, osb, 256, W_attn, b_attn, logit, 128);
    // softmax + bilinear sampling (in-place osb)
    k_sample<<<gs, blk, 0, stream>>>(qd, vproj, osb, logit, refp);
    // out = sampled @ W_out^T + b_out + query -> d_out
    k_gemm_final<<<g32, blk, 0, stream>>>(qd, osb, W_out, b_out, query, d_out);
}

// Round 11
// 238.718 us; speedup vs baseline: 2.3486x; 1.1498x over previous
//
#include <hip/hip_runtime.h>
#include <hip/hip_bf16.h>
#include <math.h>
#include <type_traits>

#define K_DIM 256
using bf16 = __hip_bfloat16;

typedef __attribute__((ext_vector_type(8))) short s8v;   // 8 bf16 (4 VGPRs)
typedef __attribute__((ext_vector_type(4))) float f4v;   // 4 f32 acc

// ---- dtype helpers ------------------------------------------------------
__device__ __forceinline__ float b2f(unsigned short u) {
    return __uint_as_float(((unsigned)u) << 16);
}
__device__ __forceinline__ unsigned short f2b(float f) {   // RNE f32->bf16
    unsigned u = __float_as_uint(f);
    unsigned r = 0x7FFFu + ((u >> 16) & 1u);
    return (unsigned short)((u + r) >> 16);
}
__device__ __forceinline__ float  ld1(const float* p) { return *p; }
__device__ __forceinline__ float  ld1(const bf16*  p) { return b2f(*(const unsigned short*)p); }
__device__ __forceinline__ void   st1(float* p, float v) { *p = v; }
__device__ __forceinline__ void   st1(bf16*  p, float v) { *(unsigned short*)p = f2b(v); }
__device__ __forceinline__ float4 ld4(const float* p) { return *(const float4*)p; }
__device__ __forceinline__ float4 ld4(const bf16*  p) {
    ushort4 u = *(const ushort4*)p;
    return make_float4(b2f(u.x), b2f(u.y), b2f(u.z), b2f(u.w));
}
__device__ __forceinline__ s8v ldw8(const bf16* p) { return *(const s8v*)p; }

// ---- runtime dtype detection (insurance; evidence says f32) -------------
__device__ __forceinline__ bool detect_bf16(const unsigned* __restrict__ qw) {
    unsigned w = qw[threadIdx.x & 63];
    unsigned t = (w >> 8) & 0x7F;
    bool hit = (t >= 0x3Bu) && (t <= 0x42u);
    unsigned long long m = __ballot(hit);
    return __popcll(m) >= 32;
}

// ---- weight pre-conversion ----------------------------------------------
// pack1: [0,65536) W_value | [65536,131072) W_off | [131072,163840) W_attn
//        | [163840,164096) b_value | [164096,164352) b_off | [164352,164480) b_attn
#define P1_TOTAL 164480
__global__ __launch_bounds__(256) void k_prep1(
    const unsigned* __restrict__ qd,
    const void* wv, const void* wo, const void* wa,
    const void* bv, const void* bo, const void* ba, bf16* __restrict__ dst)
{
    const bool isb = detect_bf16(qd);
    const int i4 = (blockIdx.x * 256 + threadIdx.x) * 4;
    if (i4 >= P1_TOTAL) return;
    const void* src; int off;
    if      (i4 < 65536)  { src = wv; off = i4; }
    else if (i4 < 131072) { src = wo; off = i4 - 65536; }
    else if (i4 < 163840) { src = wa; off = i4 - 131072; }
    else if (i4 < 164096) { src = bv; off = i4 - 163840; }
    else if (i4 < 164352) { src = bo; off = i4 - 164096; }
    else                  { src = ba; off = i4 - 164352; }
    if (isb) {
        *(ushort4*)(dst + i4) = *(const ushort4*)((const unsigned short*)src + off);
    } else {
        float4 v = *(const float4*)((const float*)src + off);
        *(ushort4*)(dst + i4) = make_ushort4(f2b(v.x), f2b(v.y), f2b(v.z), f2b(v.w));
    }
}

// pack2: [0,65536) W_out | [65536,65792) b_out   (into dead vproj region)
#define P2_TOTAL 65792
__global__ __launch_bounds__(256) void k_prep2(
    const unsigned* __restrict__ qd,
    const void* wout, const void* bout, bf16* __restrict__ dst)
{
    const bool isb = detect_bf16(qd);
    const int i4 = (blockIdx.x * 256 + threadIdx.x) * 4;
    if (i4 >= P2_TOTAL) return;
    const void* src; int off;
    if (i4 < 65536) { src = wout; off = i4; }
    else            { src = bout; off = i4 - 65536; }
    if (isb) {
        *(ushort4*)(dst + i4) = *(const ushort4*)((const unsigned short*)src + off);
    } else {
        float4 v = *(const float4*)((const float*)src + off);
        *(ushort4*)(dst + i4) = make_ushort4(f2b(v.x), f2b(v.y), f2b(v.z), f2b(v.w));
    }
}

// ---- MFMA GEMM ----------------------------------------------------------
// 32-row tiles (grid M/32), full N per block, K=256. W/bias are ALWAYS bf16
// (pre-converted) -> pure 16-B ldw8 in the k-loop, zero conversion VALU.
// A-tile contiguous -> coalesced flat staging. SPLIT: cols>=N1 -> W2/C2.
template<typename AT, typename RT, typename CT, int NFRAG, bool ADD_A2, bool SPLIT, bool ADD_RES>
__device__ __forceinline__ void mfma_gemm_body(
    unsigned short* __restrict__ As,
    const AT* __restrict__ A1, const AT* __restrict__ A2,
    const bf16* __restrict__ W1, const bf16* __restrict__ bias1, CT* __restrict__ C1, int N1,
    const bf16* __restrict__ W2, const bf16* __restrict__ bias2, bf16* __restrict__ C2, int N2,
    const RT* __restrict__ Res)
{
    const int tid = threadIdx.x;
    const int bm = blockIdx.x * 32;

    {   // stage A(+A2) -> bf16 LDS; tile contiguous -> coalesced flat loads
        const AT* t1 = A1 + (size_t)bm * K_DIM;
        if constexpr (!ADD_A2 && std::is_same<AT, bf16>::value) {
            #pragma unroll
            for (int j = 0; j < 4; ++j) {
                const int e = j * 2048 + tid * 8;
                const int row = e >> 8, col = e & 255;
                *(s8v*)&As[row * 264 + col] = *(const s8v*)(t1 + e);
            }
        } else {
            const AT* t2 = ADD_A2 ? (A2 + (size_t)bm * K_DIM) : (const AT*)0;
            #pragma unroll
            for (int j = 0; j < 8; ++j) {
                const int e = j * 1024 + tid * 4;
                float4 v = ld4(t1 + e);
                if (ADD_A2) {
                    float4 w2 = ld4(t2 + e);
                    v.x += w2.x; v.y += w2.y; v.z += w2.z; v.w += w2.w;
                }
                const int row = e >> 8, col = e & 255;
                *(ushort4*)&As[row * 264 + col] =
                    make_ushort4(f2b(v.x), f2b(v.y), f2b(v.z), f2b(v.w));
            }
        }
    }
    __syncthreads();

    const int wv = tid >> 6;
    const int lane = tid & 63;
    const int n15 = lane & 15;
    const int quad = lane >> 4;

    const bf16* Wr[NFRAG];
    int col[NFRAG];
    #pragma unroll
    for (int f = 0; f < NFRAG; ++f) {
        const int c = (wv * NFRAG + f) * 16 + n15;
        col[f] = c;
        if (SPLIT && c >= N1) Wr[f] = W2 + (size_t)(c - N1) * K_DIM;
        else                  Wr[f] = W1 + (size_t)c * K_DIM;
    }

    const f4v zz = {0.f, 0.f, 0.f, 0.f};
    f4v acc[2][NFRAG];
    #pragma unroll
    for (int mi = 0; mi < 2; ++mi)
        #pragma unroll
        for (int f = 0; f < NFRAG; ++f) acc[mi][f] = zz;

    #pragma unroll
    for (int kk = 0; kk < 8; ++kk) {
        const int k0 = kk * 32 + quad * 8;
        s8v b[NFRAG];
        #pragma unroll
        for (int f = 0; f < NFRAG; ++f) b[f] = ldw8(Wr[f] + k0);
        s8v a[2];
        #pragma unroll
        for (int mi = 0; mi < 2; ++mi)
            a[mi] = *(const s8v*)&As[(mi * 16 + n15) * 264 + k0];
        #pragma unroll
        for (int mi = 0; mi < 2; ++mi)
            #pragma unroll
            for (int f = 0; f < NFRAG; ++f)
                acc[mi][f] = __builtin_amdgcn_mfma_f32_16x16x32_bf16(a[mi], b[f], acc[mi][f], 0, 0, 0);
    }

    // C/D: col = lane&15, row = quad*4 + reg
    #pragma unroll
    for (int f = 0; f < NFRAG; ++f) {
        const int c = col[f];
        const bool hi = SPLIT && (c >= N1);
        const float bv = hi ? ld1(bias2 + (c - N1)) : ld1(bias1 + c);
        #pragma unroll
        for (int mi = 0; mi < 2; ++mi)
            #pragma unroll
            for (int r = 0; r < 4; ++r) {
                const int m = bm + mi * 16 + quad * 4 + r;
                float v = acc[mi][f][r] + bv;
                if (ADD_RES) v += ld1(Res + (size_t)m * N1 + c);
                if (hi) st1(C2 + (size_t)m * N2 + (c - N1), v);
                else    st1(C1 + (size_t)m * N1 + c, v);
            }
    }
}

template<int NFRAG, bool ADD_A2, bool SPLIT>
__global__ __launch_bounds__(256) void k_gemm(
    const unsigned* __restrict__ qd, const void* A1, const void* A2,
    const bf16* W1, const bf16* b1, bf16* C1, int N1,
    const bf16* W2, const bf16* b2, bf16* C2, int N2)
{
    __shared__ unsigned short As[32 * 264];
    if (detect_bf16(qd))
        mfma_gemm_body<bf16, float, bf16, NFRAG, ADD_A2, SPLIT, false>(As,
            (const bf16*)A1, (const bf16*)A2, W1, b1, C1, N1, W2, b2, C2, N2, nullptr);
    else
        mfma_gemm_body<float, float, bf16, NFRAG, ADD_A2, SPLIT, false>(As,
            (const float*)A1, (const float*)A2, W1, b1, C1, N1, W2, b2, C2, N2, nullptr);
}

// Final GEMM: bf16 A (sampled) + bf16 W cache; input-typed Res and d_out.
__global__ __launch_bounds__(256) void k_gemm_final(
    const unsigned* __restrict__ qd, const bf16* A1,
    const bf16* W, const bf16* bias, const void* Res, void* C)
{
    __shared__ unsigned short As[32 * 264];
    if (detect_bf16(qd))
        mfma_gemm_body<bf16, bf16, bf16, 4, false, false, true>(As,
            A1, nullptr, W, bias, (bf16*)C, 256,
            nullptr, nullptr, nullptr, 0, (const bf16*)Res);
    else
        mfma_gemm_body<bf16, float, float, 4, false, false, true>(As,
            A1, nullptr, W, bias, (float*)C, 256,
            nullptr, nullptr, nullptr, 0, (const float*)Res);
}

// ---- sampler ------------------------------------------------------------
// Block 256 = 4 queries x 64 threads; logits precomputed (bf16, in d_out).
// Tap tables: physical slot = writer_t64 + 64*tt  -> stride-16B contiguous
// writes (conflict-free). Reader (i,h) -> slot 8*(i>>1)+h+64*(i&1) ->
// 8 contiguous 16-B broadcast reads (conflict-free).
struct SampLds {
    float    sofs[4][256];
    float    slog[4][128];    // logits, softmaxed in-place
    float    sref[4][8];
    float    swgt[4][128][4];
    unsigned sidx[4][128][4];
};   // 22,656 B

__global__ __launch_bounds__(256) void k_sample(
    const unsigned* __restrict__ qd, const bf16* __restrict__ vproj,
    bf16* __restrict__ osb, const bf16* __restrict__ logits,
    const void* __restrict__ refp)
{
    __shared__ SampLds L;
    const bool isb = detect_bf16(qd);
    const int t = threadIdx.x;
    const int qg = t >> 6;
    const int t64 = t & 63;
    const int q = blockIdx.x * 4 + qg;

    {   // stage offsets (bf16 x4 -> float4 LDS)
        ushort4 u = *(const ushort4*)(osb + (size_t)q * 256 + t64 * 4);
        *(float4*)&L.sofs[qg][t64 * 4] = make_float4(b2f(u.x), b2f(u.y), b2f(u.z), b2f(u.w));
    }
    L.slog[qg][t64]      = ld1(logits + (size_t)q * 128 + t64);
    L.slog[qg][t64 + 64] = ld1(logits + (size_t)q * 128 + t64 + 64);
    if (t64 < 8)
        L.sref[qg][t64] = isb ? ld1((const bf16*)refp + (size_t)q * 8 + t64)
                              : ld1((const float*)refp + (size_t)q * 8 + t64);
    __syncthreads();

    if (t64 < 8) {   // per-head softmax over 16, in place
        float m = -1e30f;
        #pragma unroll
        for (int i = 0; i < 16; ++i) m = fmaxf(m, L.slog[qg][t64 * 16 + i]);
        float e[16];
        float s = 0.f;
        #pragma unroll
        for (int i = 0; i < 16; ++i) { e[i] = __expf(L.slog[qg][t64 * 16 + i] - m); s += e[i]; }
        const float inv = 1.f / s;
        #pragma unroll
        for (int i = 0; i < 16; ++i) L.slog[qg][t64 * 16 + i] = e[i] * inv;
    }
    __syncthreads();

    {   // tap precompute: writer lane t64 -> (h = t64&7, i = 2*(t64>>3)+tt)
        const int hh = t64 & 7;
        const int i2 = t64 >> 3;
        #pragma unroll
        for (int tt = 0; tt < 2; ++tt) {
            const int i = i2 * 2 + tt;             // (l,p) in [0,16)
            const int l = i >> 2;
            const int p = i & 3;
            const int WW = 128 >> l;
            const int st = (l == 0) ? 0 : (l == 1) ? 16384 : (l == 2) ? 20480 : 21504;
            const float ox = L.sofs[qg][hh * 32 + l * 8 + p * 2 + 0];
            const float oy = L.sofs[qg][hh * 32 + l * 8 + p * 2 + 1];
            const float gx = L.sref[qg][l * 2 + 0] * (float)WW + ox - 0.5f;
            const float gy = L.sref[qg][l * 2 + 1] * (float)WW + oy - 0.5f;
            const float x0f = floorf(gx);
            const float y0f = floorf(gy);
            const float wx = gx - x0f;
            const float wy = gy - y0f;
            const int x0 = (int)x0f;
            const int y0 = (int)y0f;
            const float aw = L.slog[qg][hh * 16 + i];
            const float vx0 = (x0 >= 0 && x0 < WW) ? 1.f : 0.f;
            const float vx1 = (x0 + 1 >= 0 && x0 + 1 < WW) ? 1.f : 0.f;
            const float vy0 = (y0 >= 0 && y0 < WW) ? 1.f : 0.f;
            const float vy1 = (y0 + 1 >= 0 && y0 + 1 < WW) ? 1.f : 0.f;
            const int xc0 = min(max(x0, 0), WW - 1);
            const int xc1 = min(max(x0 + 1, 0), WW - 1);
            const int yc0 = min(max(y0, 0), WW - 1);
            const int yc1 = min(max(y0 + 1, 0), WW - 1);
            const int slot = t64 + (tt << 6);       // contiguous 16B/lane writes
            *(float4*)L.swgt[qg][slot] = make_float4(
                (1.f - wx) * (1.f - wy) * aw * vx0 * vy0,
                wx * (1.f - wy) * aw * vx1 * vy0,
                (1.f - wx) * wy * aw * vx0 * vy1,
                wx * wy * aw * vx1 * vy1);
            *(uint4*)L.sidx[qg][slot] = make_uint4(
                (unsigned)(st + yc0 * WW + xc0) * 512u,
                (unsigned)(st + yc0 * WW + xc1) * 512u,
                (unsigned)(st + yc1 * WW + xc0) * 512u,
                (unsigned)(st + yc1 * WW + xc1) * 512u);
        }
    }
    __syncthreads();

    // gather: 4 channels/thread, ushort4 loads
    const int h = t64 >> 3;
    const int dg = t64 & 7;
    const unsigned chb = (unsigned)(h * 32 + dg * 4) * 2u;
    const char* vb = (const char*)vproj;
    float a0 = 0.f, a1 = 0.f, a2 = 0.f, a3 = 0.f;
    #pragma unroll
    for (int i = 0; i < 16; ++i) {
        const int slot = ((i >> 1) << 3) | h | ((i & 1) << 6);
        const uint4  iv = *(const uint4*)L.sidx[qg][slot];
        const float4 wv = *(const float4*)L.swgt[qg][slot];
        {
            ushort4 pv = *(const ushort4*)(vb + (size_t)(iv.x + chb));
            a0 = fmaf(wv.x, b2f(pv.x), a0); a1 = fmaf(wv.x, b2f(pv.y), a1);
            a2 = fmaf(wv.x, b2f(pv.z), a2); a3 = fmaf(wv.x, b2f(pv.w), a3);
        }
        {
            ushort4 pv = *(const ushort4*)(vb + (size_t)(iv.y + chb));
            a0 = fmaf(wv.y, b2f(pv.x), a0); a1 = fmaf(wv.y, b2f(pv.y), a1);
            a2 = fmaf(wv.y, b2f(pv.z), a2); a3 = fmaf(wv.y, b2f(pv.w), a3);
        }
        {
            ushort4 pv = *(const ushort4*)(vb + (size_t)(iv.z + chb));
            a0 = fmaf(wv.z, b2f(pv.x), a0); a1 = fmaf(wv.z, b2f(pv.y), a1);
            a2 = fmaf(wv.z, b2f(pv.z), a2); a3 = fmaf(wv.z, b2f(pv.w), a3);
        }
        {
            ushort4 pv = *(const ushort4*)(vb + (size_t)(iv.w + chb));
            a0 = fmaf(wv.w, b2f(pv.x), a0); a1 = fmaf(wv.w, b2f(pv.y), a1);
            a2 = fmaf(wv.w, b2f(pv.z), a2); a3 = fmaf(wv.w, b2f(pv.w), a3);
        }
    }
    *(ushort4*)(osb + (size_t)q * 256 + h * 32 + dg * 4) =
        make_ushort4(f2b(a0), f2b(a1), f2b(a2), f2b(a3));
}

extern "C" void kernel_launch(void* const* d_in, const int* in_sizes, int n_in,
                              void* d_out, int out_size, void* d_ws, size_t ws_size,
                              hipStream_t stream) {
    const void* query     = d_in[0];
    const void* query_pos = d_in[1];
    const void* value     = d_in[2];
    const void* refp      = d_in[3];
    const void* W_value = d_in[5];
    const void* b_value = d_in[6];
    const void* W_off   = d_in[7];
    const void* b_off   = d_in[8];
    const void* W_attn  = d_in[9];
    const void* b_attn  = d_in[10];
    const void* W_out   = d_in[11];
    const void* b_out   = d_in[12];
    const unsigned* qd = (const unsigned*)d_in[0];

    const int M = in_sizes[0] / 256;   // 21760 = 32*680 = 4*5440
    char* wsb = (char*)d_ws;

    // ws: vproj | osb (offsets->sampled in-place).
    bf16* vproj = (bf16*)wsb;                      // M*512 B
    bf16* osb   = (bf16*)(wsb + (size_t)M * 512);  // M*512 B
    // d_out scratch: logits [0, M*256 B) ; W-cache pack1 at +8 MB.
    bf16* logit = (bf16*)d_out;
    bf16* wc1   = (bf16*)((char*)d_out + (8u << 20));
    // pack1 layout offsets (elements):
    const bf16* c_wv = wc1;
    const bf16* c_wo = wc1 + 65536;
    const bf16* c_wa = wc1 + 131072;
    const bf16* c_bv = wc1 + 163840;
    const bf16* c_bo = wc1 + 164096;
    const bf16* c_ba = wc1 + 164352;
    // pack2 (W_out) goes into the vproj region once vproj is dead.
    bf16* wc2 = vproj;

    dim3 blk(256, 1, 1);
    dim3 g32((unsigned)(M / 32), 1, 1);
    dim3 gs((unsigned)(M / 4), 1, 1);

    // 0) weights -> bf16 caches
    k_prep1<<<dim3((P1_TOTAL / 4 + 255) / 256), blk, 0, stream>>>(qd,
        W_value, W_off, W_attn, b_value, b_off, b_attn, wc1);
    // 1) v = value @ W_value^T + b_value -> vproj
    k_gemm<4, false, false><<<g32, blk, 0, stream>>>(qd, value, nullptr,
        c_wv, c_bv, vproj, 256, nullptr, nullptr, nullptr, 0);
    // 2) fused: (q+qp) @ [W_off | W_attn]^T -> osb (256) | logits (128)
    k_gemm<6, true, true><<<g32, blk, 0, stream>>>(qd, query, query_pos,
        c_wo, c_bo, osb, 256, c_wa, c_ba, logit, 128);
    // 3) softmax + bilinear sampling (in-place osb)
    k_sample<<<gs, blk, 0, stream>>>(qd, vproj, osb, logit, refp);
    // 4) W_out -> bf16 into dead vproj region
    k_prep2<<<dim3((P2_TOTAL / 4 + 255) / 256), blk, 0, stream>>>(qd, W_out, b_out, wc2);
    // 5) out = sampled @ W_out^T + b_out + query -> d_out
    k_gemm_final<<<g32, blk, 0, stream>>>(qd, osb, wc2, wc2 + 65536, query, d_out);
}